// Round 6
// baseline (4662.776 us; speedup 1.0000x reference)
//
#include <hip/hip_runtime.h>
#include <math.h>

#define N 64
#define NP 65            // odd pitch: column access As[lane][p] is 2-way (free)
#define SWEEPS 6
#define EPSV 1e-3
#define MAXEIG 1000.0

// EIGHT 64-lane waves per 64x64 symmetric matrix (512 threads/block).
// Two-sided cyclic Jacobi, tournament ordering; 32 pairs/round, 4 per wave.
// Round-5 analysis: issue-bound (VALU 68%, LDS pipe only ~23%); fixes here:
//  - 8 waves/matrix halves per-wave issue count; 32 waves/CU (VGPR<=64).
//  - row & Vt phases process 2 adjacent columns per lane (lanes 0..31 pair A,
//    lanes 32..63 pair B) -> adjacent LDS loads merge into ds_read2_b32 /
//    ds_write2_b32: half the LDS issue count at same bytes.
//  - Vt pitch 65: epilogue (Rayleigh + reconstruction) reads Vt rows/broadcasts
//    directly -> the V-transpose pass and the in-place scale pass are deleted.
//  - coeffs per-wave (lanes<4) so no cross-wave read of rows another wave is
//    rewriting; gather-all-then-write-all in every phase (alias-chain fix).
__global__ __launch_bounds__(512, 8)
void spd_log_kernel(const float* __restrict__ x, float* __restrict__ out) {
    __shared__ float As[N][NP];     // A during Jacobi
    __shared__ float Vt[N][NP];     // V^T; row k = eigenvector k
    __shared__ float farr[N];
    __shared__ double2 part[7][N];  // Rayleigh partials of waves 1..7

    const int tid  = (int)threadIdx.x;
    const int lane = tid & 63;
    const int wid  = __builtin_amdgcn_readfirstlane(tid >> 6);  // 0..7
    const int half = lane >> 5;          // 0: pair 2t, 1: pair 2t+1
    const int c2   = (lane & 31) * 2;    // two adjacent columns per lane
    const size_t mat = blockIdx.x;
    const float* __restrict__ xm = x + mat * (size_t)(N * N);
    float* __restrict__ om = out + mat * (size_t)(N * N);

#pragma unroll
    for (int t = 0; t < 8; ++t) {
        const int r2 = wid * 8 + t;
        As[r2][lane] = xm[r2 * N + lane];
        Vt[r2][lane] = (r2 == lane) ? 1.0f : 0.0f;
    }
    __syncthreads();

    for (int sweep = 0; sweep < SWEEPS; ++sweep) {
        for (int r = 0; r < N - 1; ++r) {
            // ---- coefficients for this wave's 4 pairs (lanes 0..3) ----
            float cv = 1.0f, sv = 0.0f;
            if (lane < 4) {
                const int i = wid * 4 + lane;
                int a = i - 1 + r; if (a >= 63) a -= 63;
                const int p = (i == 0) ? 0 : 1 + a;
                int b = 62 - i + r; if (b >= 63) b -= 63;
                const int q = 1 + b;
                const float app = As[p][p], aqq = As[q][q], apq = As[p][q];
                if (apq != 0.0f) {
                    const float tau = (aqq - app) / (2.0f * apq);
                    const float at = fabsf(tau);
                    float t2 = 1.0f / (at + sqrtf(1.0f + at * at));
                    t2 = copysignf(t2, tau);
                    cv = 1.0f / sqrtf(1.0f + t2 * t2);
                    sv = t2 * cv;
                }
            }
            // per-lane (c,s) for row/Vt phases: pair (wid*4 + 2t + half)
            const float c0 = __shfl(cv, half),     s0 = __shfl(sv, half);
            const float c1 = __shfl(cv, 2 + half), s1 = __shfl(sv, 2 + half);
            // pair indices (VGPR, half-dependent)
            const int i0 = wid * 4 + half;
            int a0 = i0 - 1 + r; if (a0 >= 63) a0 -= 63;
            const int p0 = (i0 == 0) ? 0 : 1 + a0;
            int b0 = 62 - i0 + r; if (b0 >= 63) b0 -= 63;
            const int q0 = 1 + b0;
            const int i1 = i0 + 2;                 // >= 2, never 0
            int a1 = i1 - 1 + r; if (a1 >= 63) a1 -= 63;
            const int p1 = 1 + a1;
            int b1 = 62 - i1 + r; if (b1 >= 63) b1 -= 63;
            const int q1 = 1 + b1;

            // ---- ROW phase: gather all 8, compute, scatter all 8 ----
            const float rp00 = As[p0][c2], rp01 = As[p0][c2 + 1];
            const float rq00 = As[q0][c2], rq01 = As[q0][c2 + 1];
            const float rp10 = As[p1][c2], rp11 = As[p1][c2 + 1];
            const float rq10 = As[q1][c2], rq11 = As[q1][c2 + 1];
            As[p0][c2]     = c0 * rp00 - s0 * rq00;
            As[p0][c2 + 1] = c0 * rp01 - s0 * rq01;
            As[q0][c2]     = s0 * rp00 + c0 * rq00;
            As[q0][c2 + 1] = s0 * rp01 + c0 * rq01;
            As[p1][c2]     = c1 * rp10 - s1 * rq10;
            As[p1][c2 + 1] = c1 * rp11 - s1 * rq11;
            As[q1][c2]     = s1 * rp10 + c1 * rq10;
            As[q1][c2 + 1] = s1 * rp11 + c1 * rq11;
            __syncthreads();

            // ---- COL phase on A: scalar (c,s) via readlane (SGPR) ----
            float ca[4], sa[4];
#pragma unroll
            for (int ii = 0; ii < 4; ++ii) {
                ca[ii] = __uint_as_float(__builtin_amdgcn_readlane(__float_as_uint(cv), ii));
                sa[ii] = __uint_as_float(__builtin_amdgcn_readlane(__float_as_uint(sv), ii));
            }
            int pa[4], qa[4];   // uniform (wid SGPR, r loop-uniform)
#pragma unroll
            for (int ii = 0; ii < 4; ++ii) {
                const int i = wid * 4 + ii;
                int a = i - 1 + r; if (a >= 63) a -= 63;
                pa[ii] = (i == 0) ? 0 : 1 + a;
                int b = 62 - i + r; if (b >= 63) b -= 63;
                qa[ii] = 1 + b;
            }
            float cp[4], cq[4];
#pragma unroll
            for (int ii = 0; ii < 4; ++ii) {
                cp[ii] = As[lane][pa[ii]];
                cq[ii] = As[lane][qa[ii]];
            }
#pragma unroll
            for (int ii = 0; ii < 4; ++ii) {
                As[lane][pa[ii]] = ca[ii] * cp[ii] - sa[ii] * cq[ii];
                As[lane][qa[ii]] = sa[ii] * cp[ii] + ca[ii] * cq[ii];
            }

            // ---- Vt row phase (same pairs/coeffs as row phase) ----
            const float vp00 = Vt[p0][c2], vp01 = Vt[p0][c2 + 1];
            const float vq00 = Vt[q0][c2], vq01 = Vt[q0][c2 + 1];
            const float vp10 = Vt[p1][c2], vp11 = Vt[p1][c2 + 1];
            const float vq10 = Vt[q1][c2], vq11 = Vt[q1][c2 + 1];
            Vt[p0][c2]     = c0 * vp00 - s0 * vq00;
            Vt[p0][c2 + 1] = c0 * vp01 - s0 * vq01;
            Vt[q0][c2]     = s0 * vp00 + c0 * vq00;
            Vt[q0][c2 + 1] = s0 * vp01 + c0 * vq01;
            Vt[p1][c2]     = c1 * vp10 - s1 * vq10;
            Vt[p1][c2 + 1] = c1 * vp11 - s1 * vq11;
            Vt[q1][c2]     = s1 * vp10 + c1 * vq10;
            Vt[q1][c2 + 1] = s1 * vp11 + c1 * vq11;
            __syncthreads();
        }
    }

    // ---- fp64 Rayleigh vs ORIGINAL input; 8 rows per wave.
    //      eigvec `lane` = row `lane` of Vt (contiguous, 2-way-free reads) ----
    const int r0 = wid * 8;
    {
        float vr[8];
#pragma unroll
        for (int t = 0; t < 8; ++t) vr[t] = Vt[lane][r0 + t];
        double nrm = 0.0, acc = 0.0;
#pragma unroll
        for (int t = 0; t < 8; ++t) nrm += (double)vr[t] * (double)vr[t];
        for (int c = 0; c < N; ++c) {
            const double vc = (double)Vt[lane][c];
            double inner = 0.0;
#pragma unroll
            for (int t = 0; t < 8; ++t)
                inner += (double)xm[(r0 + t) * N + c] * (double)vr[t];
            acc += vc * inner;
        }
        if (wid > 0) part[wid - 1][lane] = make_double2(acc, nrm);
        __syncthreads();
        if (wid == 0) {
#pragma unroll
            for (int k = 0; k < 7; ++k) {
                acc += part[k][lane].x;
                nrm += part[k][lane].y;
            }
            double wv = acc / nrm;
            wv = fmin(fmax(wv, (double)EPSV), (double)MAXEIG);
            farr[lane] = (float)log(wv);
        }
    }
    __syncthreads();

    // ---- reconstruct Out[r][lane] = sum_j Vt[j][r] * f_j * Vt[j][lane];
    //      8 rows per wave; Vt[j][r0+t] is a uniform broadcast read ----
    {
        float acc8[8];
#pragma unroll
        for (int t = 0; t < 8; ++t) acc8[t] = 0.0f;
        for (int j = 0; j < N; ++j) {
            const float gj = Vt[j][lane] * farr[j];
#pragma unroll
            for (int t = 0; t < 8; ++t)
                acc8[t] += Vt[j][r0 + t] * gj;
        }
#pragma unroll
        for (int t = 0; t < 8; ++t)
            om[(r0 + t) * N + lane] = acc8[t];
    }
}

extern "C" void kernel_launch(void* const* d_in, const int* in_sizes, int n_in,
                              void* d_out, int out_size, void* d_ws, size_t ws_size,
                              hipStream_t stream) {
    const float* x = (const float*)d_in[0];
    float* out = (float*)d_out;
    const int nmat = in_sizes[0] / (N * N);
    spd_log_kernel<<<dim3(nmat), dim3(512), 0, stream>>>(x, out);
}

// Round 7
// 3899.723 us; speedup vs baseline: 1.1957x; 1.1957x over previous
//
#include <hip/hip_runtime.h>
#include <math.h>

#define N 64
#define NP 65            // odd pitch: (row + col)%32 spreads banks; all phases conflict-free
#define SWEEPS 6
#define EPSV 1e-3
#define MAXEIG 1000.0

// EIGHT 64-lane waves per 64x64 symmetric matrix (512 threads/block).
// Two-sided cyclic Jacobi, tournament ordering; 32 pairs/round, 4 per wave.
// Round-6 lesson: paired-column (stride-2) LDS addressing caused 4-way bank
// conflicts (SQ_LDS_BANK_CONFLICT 4.6e7 -> 8.3e8, +1.35ms LDS serialization).
// This round: per-lane single-column addressing everywhere (bank=(p+lane)%32,
// conflict-free), 8-wave split kept, Rayleigh partial buffer overlaid on the
// dead A storage so LDS = 32.8 KB -> 4 blocks/CU = 32 waves/CU (100% cap).
__global__ __launch_bounds__(512, 8)
void spd_log_kernel(const float* __restrict__ x, float* __restrict__ out) {
    __shared__ __align__(16) float As[N][NP];  // A during Jacobi; scratch after
    __shared__ float Vt[N][NP];                // V^T; row k = eigenvector k
    __shared__ float farr[N];

    const int tid  = (int)threadIdx.x;
    const int lane = tid & 63;
    const int wid  = __builtin_amdgcn_readfirstlane(tid >> 6);  // 0..7
    const size_t mat = blockIdx.x;
    const float* __restrict__ xm = x + mat * (size_t)(N * N);
    float* __restrict__ om = out + mat * (size_t)(N * N);

#pragma unroll
    for (int t = 0; t < 8; ++t) {
        const int r2 = wid * 8 + t;
        As[r2][lane] = xm[r2 * N + lane];
        Vt[r2][lane] = (r2 == lane) ? 1.0f : 0.0f;
    }
    __syncthreads();

    for (int sweep = 0; sweep < SWEEPS; ++sweep) {
        for (int r = 0; r < N - 1; ++r) {
            // ---- coefficients for this wave's 4 pairs (lanes 0..3).
            //      reads only rows p,q owned by this wave -> no barrier needed.
            float cv = 1.0f, sv = 0.0f;
            if (lane < 4) {
                const int i = wid * 4 + lane;
                int a = i - 1 + r; if (a >= 63) a -= 63;
                const int p = (i == 0) ? 0 : 1 + a;
                int b = 62 - i + r; if (b >= 63) b -= 63;
                const int q = 1 + b;
                const float app = As[p][p], aqq = As[q][q], apq = As[p][q];
                if (apq != 0.0f) {
                    const float tau = (aqq - app) / (2.0f * apq);
                    const float at = fabsf(tau);
                    float t2 = 1.0f / (at + sqrtf(1.0f + at * at));
                    t2 = copysignf(t2, tau);
                    cv = 1.0f / sqrtf(1.0f + t2 * t2);
                    sv = t2 * cv;
                }
            }
            // (c,s) -> SGPR broadcasts; pair indices -> SALU (wid is scalar)
            float ca[4], sa[4];
#pragma unroll
            for (int ii = 0; ii < 4; ++ii) {
                ca[ii] = __uint_as_float(__builtin_amdgcn_readlane(__float_as_uint(cv), ii));
                sa[ii] = __uint_as_float(__builtin_amdgcn_readlane(__float_as_uint(sv), ii));
            }
            int pa[4], qa[4];
#pragma unroll
            for (int ii = 0; ii < 4; ++ii) {
                const int i = wid * 4 + ii;
                int a = i - 1 + r; if (a >= 63) a -= 63;
                pa[ii] = (i == 0) ? 0 : 1 + a;
                int b = 62 - i + r; if (b >= 63) b -= 63;
                qa[ii] = 1 + b;
            }

            // ---- ROW phase: lane = column; gather all, then write all ----
            float rp[4], rq[4];
#pragma unroll
            for (int ii = 0; ii < 4; ++ii) {
                rp[ii] = As[pa[ii]][lane];
                rq[ii] = As[qa[ii]][lane];
            }
#pragma unroll
            for (int ii = 0; ii < 4; ++ii) {
                As[pa[ii]][lane] = ca[ii] * rp[ii] - sa[ii] * rq[ii];
                As[qa[ii]][lane] = sa[ii] * rp[ii] + ca[ii] * rq[ii];
            }
            __syncthreads();

            // ---- COL phase on A (lane = row) + Vt row rotation (own rows,
            //      no cross-wave hazard): gather all 8, write all 8 ----
            float cp[4], cq[4], vp[4], vq[4];
#pragma unroll
            for (int ii = 0; ii < 4; ++ii) {
                cp[ii] = As[lane][pa[ii]];
                cq[ii] = As[lane][qa[ii]];
                vp[ii] = Vt[pa[ii]][lane];
                vq[ii] = Vt[qa[ii]][lane];
            }
#pragma unroll
            for (int ii = 0; ii < 4; ++ii) {
                As[lane][pa[ii]] = ca[ii] * cp[ii] - sa[ii] * cq[ii];
                As[lane][qa[ii]] = sa[ii] * cp[ii] + ca[ii] * cq[ii];
                Vt[pa[ii]][lane] = ca[ii] * vp[ii] - sa[ii] * vq[ii];
                Vt[qa[ii]][lane] = sa[ii] * vp[ii] + ca[ii] * vq[ii];
            }
            __syncthreads();
        }
    }

    // A is dead from here on -> overlay Rayleigh partials on its storage.
    double2* part = reinterpret_cast<double2*>(&As[0][0]);  // 7*64*16 B < 16.6 KB

    // ---- fp64 Rayleigh vs ORIGINAL input; eigvec `lane` = Vt row `lane`;
    //      each wave covers 8 rows of the quadratic form ----
    const int r0 = wid * 8;
    {
        float vr[8];
#pragma unroll
        for (int t = 0; t < 8; ++t) vr[t] = Vt[lane][r0 + t];
        double nrm = 0.0, acc = 0.0;
#pragma unroll
        for (int t = 0; t < 8; ++t) nrm += (double)vr[t] * (double)vr[t];
        for (int c = 0; c < N; ++c) {
            const double vc = (double)Vt[lane][c];
            double inner = 0.0;
#pragma unroll
            for (int t = 0; t < 8; ++t)
                inner += (double)xm[(r0 + t) * N + c] * (double)vr[t];
            acc += vc * inner;
        }
        if (wid > 0) part[(wid - 1) * N + lane] = make_double2(acc, nrm);
        __syncthreads();
        if (wid == 0) {
#pragma unroll
            for (int k = 0; k < 7; ++k) {
                acc += part[k * N + lane].x;
                nrm += part[k * N + lane].y;
            }
            double wv = acc / nrm;
            wv = fmin(fmax(wv, (double)EPSV), (double)MAXEIG);
            farr[lane] = (float)log(wv);
        }
    }
    __syncthreads();

    // ---- reconstruct Out[r][lane] = sum_j Vt[j][r] * f_j * Vt[j][lane];
    //      8 rows per wave; Vt[j][r0+t] is a uniform broadcast read ----
    {
        float acc8[8];
#pragma unroll
        for (int t = 0; t < 8; ++t) acc8[t] = 0.0f;
        for (int j = 0; j < N; ++j) {
            const float gj = Vt[j][lane] * farr[j];
#pragma unroll
            for (int t = 0; t < 8; ++t)
                acc8[t] += Vt[j][r0 + t] * gj;
        }
#pragma unroll
        for (int t = 0; t < 8; ++t)
            om[(r0 + t) * N + lane] = acc8[t];
    }
}

extern "C" void kernel_launch(void* const* d_in, const int* in_sizes, int n_in,
                              void* d_out, int out_size, void* d_ws, size_t ws_size,
                              hipStream_t stream) {
    const float* x = (const float*)d_in[0];
    float* out = (float*)d_out;
    const int nmat = in_sizes[0] / (N * N);
    spd_log_kernel<<<dim3(nmat), dim3(512), 0, stream>>>(x, out);
}

// Round 9
// 3495.227 us; speedup vs baseline: 1.3340x; 1.1157x over previous
//
#include <hip/hip_runtime.h>
#include <math.h>

#define N 64
#define NP 65            // odd pitch: row & column phases conflict-free
#define SWEEPS 6         // 5 sweeps FAILED (absmax 0.30): residual ~3e-4 * log-amplification
#define EPSV 1e-3
#define MAXEIG 1000.0

// EIGHT 64-lane waves per 64x64 symmetric matrix (512 threads/block).
// Two-sided cyclic Jacobi, tournament ordering; 32 pairs/round, 4 per wave.
// VALU-bound regime (round 7: VALUBusy 92%). VALU cuts kept from round 8:
//  - fast-math coefficient path (v_rcp/v_sqrt/v_rsq single instrs, branchless
//    with |apq| threshold select) instead of IEEE div/sqrt expansions.
//    (angle err ~1e-7/rotation -> V non-orthogonality ~2e-6 total: safe)
//  - A and Vt in ONE LDS buffer: Vt row p at constant byte offset from A row
//    p, so the Vt phase reuses row-phase address VGPRs via imm offsets.
// SWEEPS reverted 5 -> 6: five sweeps left ~3e-4 off-diag residual in the
// worst matrix; log near eps amplifies x1000 -> 0.30 absmax. Six converges
// (6/7/8/10 all bit-identical 0.03125).
__global__ __launch_bounds__(512, 8)
void spd_log_kernel(const float* __restrict__ x, float* __restrict__ out) {
    __shared__ __align__(16) float buf[2 * N * NP];  // [0,64): A ; [64,128): Vt
    __shared__ float farr[N];

    float* const As_ = buf;
    float* const Vt_ = buf + N * NP;   // Vt row k = eigenvector k

    const int tid  = (int)threadIdx.x;
    const int lane = tid & 63;
    const int wid  = __builtin_amdgcn_readfirstlane(tid >> 6);  // 0..7
    const size_t mat = blockIdx.x;
    const float* __restrict__ xm = x + mat * (size_t)(N * N);
    float* __restrict__ om = out + mat * (size_t)(N * N);

#pragma unroll
    for (int t = 0; t < 8; ++t) {
        const int r2 = wid * 8 + t;
        As_[r2 * NP + lane] = xm[r2 * N + lane];
        Vt_[r2 * NP + lane] = (r2 == lane) ? 1.0f : 0.0f;
    }
    __syncthreads();

    for (int sweep = 0; sweep < SWEEPS; ++sweep) {
        for (int r = 0; r < N - 1; ++r) {
            // ---- coefficients for this wave's 4 pairs (lanes 0..3);
            //      reads only rows/cols this wave owns -> no barrier ----
            float cv = 1.0f, sv = 0.0f;
            if (lane < 4) {
                const int i = wid * 4 + lane;
                int a = i - 1 + r; if (a >= 63) a -= 63;
                const int p = (i == 0) ? 0 : 1 + a;
                int b = 62 - i + r; if (b >= 63) b -= 63;
                const int q = 1 + b;
                const float app = As_[p * NP + p];
                const float aqq = As_[q * NP + q];
                const float apq = As_[p * NP + q];
                // branchless fast-math rotation coefficients
                const float tau = (aqq - app) * (0.5f * __builtin_amdgcn_rcpf(apq));
                const float at  = fabsf(tau);
                float t2 = __builtin_amdgcn_rcpf(at + __builtin_amdgcn_sqrtf(fmaf(at, at, 1.0f)));
                t2 = copysignf(t2, tau);
                const float cc = __builtin_amdgcn_rsqf(fmaf(t2, t2, 1.0f));
                // |apq| ~ 0 (incl. exactly 0 with app==aqq -> NaN path): identity
                const bool tiny = !(fabsf(apq) > 1e-30f);
                cv = tiny ? 1.0f : cc;
                sv = tiny ? 0.0f : t2 * cc;
            }
            // (c,s) -> SGPR broadcasts; pair indices -> SALU (wid scalar)
            float ca[4], sa[4];
#pragma unroll
            for (int ii = 0; ii < 4; ++ii) {
                ca[ii] = __uint_as_float(__builtin_amdgcn_readlane(__float_as_uint(cv), ii));
                sa[ii] = __uint_as_float(__builtin_amdgcn_readlane(__float_as_uint(sv), ii));
            }
            int pa[4], qa[4];
#pragma unroll
            for (int ii = 0; ii < 4; ++ii) {
                const int i = wid * 4 + ii;
                int a = i - 1 + r; if (a >= 63) a -= 63;
                pa[ii] = (i == 0) ? 0 : 1 + a;
                int b = 62 - i + r; if (b >= 63) b -= 63;
                qa[ii] = 1 + b;
            }

            // ---- ROW phase: lane = column; gather all, then write all ----
            float rp[4], rq[4];
#pragma unroll
            for (int ii = 0; ii < 4; ++ii) {
                rp[ii] = As_[pa[ii] * NP + lane];
                rq[ii] = As_[qa[ii] * NP + lane];
            }
#pragma unroll
            for (int ii = 0; ii < 4; ++ii) {
                As_[pa[ii] * NP + lane] = ca[ii] * rp[ii] - sa[ii] * rq[ii];
                As_[qa[ii] * NP + lane] = sa[ii] * rp[ii] + ca[ii] * rq[ii];
            }
            __syncthreads();

            // ---- COL phase on A (lane = row) + Vt rotation (wave-own rows;
            //      Vt addr = row-phase addr + const offset -> imm folded) ----
            float cp[4], cq[4], vp[4], vq[4];
#pragma unroll
            for (int ii = 0; ii < 4; ++ii) {
                cp[ii] = As_[lane * NP + pa[ii]];
                cq[ii] = As_[lane * NP + qa[ii]];
                vp[ii] = Vt_[pa[ii] * NP + lane];
                vq[ii] = Vt_[qa[ii] * NP + lane];
            }
#pragma unroll
            for (int ii = 0; ii < 4; ++ii) {
                As_[lane * NP + pa[ii]] = ca[ii] * cp[ii] - sa[ii] * cq[ii];
                As_[lane * NP + qa[ii]] = sa[ii] * cp[ii] + ca[ii] * cq[ii];
                Vt_[pa[ii] * NP + lane] = ca[ii] * vp[ii] - sa[ii] * vq[ii];
                Vt_[qa[ii] * NP + lane] = sa[ii] * vp[ii] + ca[ii] * vq[ii];
            }
            __syncthreads();
        }
    }

    // A is dead from here -> overlay Rayleigh partials on its storage.
    double2* part = reinterpret_cast<double2*>(As_);  // 7*64*16 B < 16.6 KB

    // ---- fp64 Rayleigh vs ORIGINAL input; eigvec `lane` = Vt row `lane`;
    //      each wave covers 8 rows of the quadratic form ----
    const int r0 = wid * 8;
    {
        float vr[8];
#pragma unroll
        for (int t = 0; t < 8; ++t) vr[t] = Vt_[lane * NP + r0 + t];
        double nrm = 0.0, acc = 0.0;
#pragma unroll
        for (int t = 0; t < 8; ++t) nrm += (double)vr[t] * (double)vr[t];
        for (int c = 0; c < N; ++c) {
            const double vc = (double)Vt_[lane * NP + c];
            double inner = 0.0;
#pragma unroll
            for (int t = 0; t < 8; ++t)
                inner += (double)xm[(r0 + t) * N + c] * (double)vr[t];
            acc += vc * inner;
        }
        if (wid > 0) part[(wid - 1) * N + lane] = make_double2(acc, nrm);
        __syncthreads();
        if (wid == 0) {
#pragma unroll
            for (int k = 0; k < 7; ++k) {
                acc += part[k * N + lane].x;
                nrm += part[k * N + lane].y;
            }
            double wv = acc / nrm;
            wv = fmin(fmax(wv, (double)EPSV), (double)MAXEIG);
            farr[lane] = (float)log(wv);
        }
    }
    __syncthreads();

    // ---- reconstruct Out[r][lane] = sum_j Vt[j][r] * f_j * Vt[j][lane];
    //      8 rows per wave; Vt[j][r0+t] is a uniform broadcast read ----
    {
        float acc8[8];
#pragma unroll
        for (int t = 0; t < 8; ++t) acc8[t] = 0.0f;
        for (int j = 0; j < N; ++j) {
            const float gj = Vt_[j * NP + lane] * farr[j];
#pragma unroll
            for (int t = 0; t < 8; ++t)
                acc8[t] += Vt_[j * NP + r0 + t] * gj;
        }
#pragma unroll
        for (int t = 0; t < 8; ++t)
            om[(r0 + t) * N + lane] = acc8[t];
    }
}

extern "C" void kernel_launch(void* const* d_in, const int* in_sizes, int n_in,
                              void* d_out, int out_size, void* d_ws, size_t ws_size,
                              hipStream_t stream) {
    const float* x = (const float*)d_in[0];
    float* out = (float*)d_out;
    const int nmat = in_sizes[0] / (N * N);
    spd_log_kernel<<<dim3(nmat), dim3(512), 0, stream>>>(x, out);
}